// Round 5
// baseline (473.610 us; speedup 1.0000x reference)
//
#include <hip/hip_runtime.h>
#include <math.h>

typedef __attribute__((ext_vector_type(8))) short short8;
typedef __bf16 bf16x8 __attribute__((ext_vector_type(8)));
typedef __attribute__((ext_vector_type(4))) float f32x4;
typedef __attribute__((ext_vector_type(16))) float f32x16;

__device__ inline short f2bf(float f) {
    unsigned u = __builtin_bit_cast(unsigned, f);
    u += 0x7fff + ((u >> 16) & 1);   // round-to-nearest-even
    return (short)(u >> 16);
}
__device__ inline float bf2f(short h) {
    return __builtin_bit_cast(float, ((unsigned)(unsigned short)h) << 16);
}
__device__ inline float gelu_f(float x) {
    return 0.5f * x * (1.f + erff(x * 0.70710678118654752f));
}

// ---------------------------------------------------------------------------
// W f32 [K][N] -> Wt bf16 [N][K]
// ---------------------------------------------------------------------------
__global__ __launch_bounds__(256) void wcast_t(
    const float* __restrict__ W, short* __restrict__ Wt, int K, int N)
{
    __shared__ float T[32][33];
    int k0 = blockIdx.y * 32, n0 = blockIdx.x * 32;
    int tid = threadIdx.x;
    int r = tid >> 3, c4 = (tid & 7) * 4;
    float4 v = *(const float4*)&W[(size_t)(k0 + r) * N + n0 + c4];
    T[r][c4 + 0] = v.x; T[r][c4 + 1] = v.y; T[r][c4 + 2] = v.z; T[r][c4 + 3] = v.w;
    __syncthreads();
    short4 o;
    o.x = f2bf(T[c4 + 0][r]);
    o.y = f2bf(T[c4 + 1][r]);
    o.z = f2bf(T[c4 + 2][r]);
    o.w = f2bf(T[c4 + 3][r]);
    *(short4*)&Wt[(size_t)(n0 + r) * K + k0 + c4] = o;
}

// W f32 [K][N] -> W3t bf16 [N][3K] = [hi | lo | hi]
__global__ __launch_bounds__(256) void wcast_t3(
    const float* __restrict__ W, short* __restrict__ W3t, int K, int N)
{
    __shared__ float T[32][33];
    int k0 = blockIdx.y * 32, n0 = blockIdx.x * 32;
    int tid = threadIdx.x;
    int r = tid >> 3, c4 = (tid & 7) * 4;
    float4 v = *(const float4*)&W[(size_t)(k0 + r) * N + n0 + c4];
    T[r][c4 + 0] = v.x; T[r][c4 + 1] = v.y; T[r][c4 + 2] = v.z; T[r][c4 + 3] = v.w;
    __syncthreads();
    short4 hi, lo;
    float f;
    f = T[c4 + 0][r]; hi.x = f2bf(f); lo.x = f2bf(f - bf2f(hi.x));
    f = T[c4 + 1][r]; hi.y = f2bf(f); lo.y = f2bf(f - bf2f(hi.y));
    f = T[c4 + 2][r]; hi.z = f2bf(f); lo.z = f2bf(f - bf2f(hi.z));
    f = T[c4 + 3][r]; hi.w = f2bf(f); lo.w = f2bf(f - bf2f(hi.w));
    short* d = W3t + (size_t)(n0 + r) * 3 * K + k0 + c4;
    *(short4*)d = hi;
    *(short4*)(d + K) = lo;
    *(short4*)(d + 2 * K) = hi;
}

// ---------------------------------------------------------------------------
// bf16 MFMA GEMM, B^T layout (unchanged from R4 — proven).
// ---------------------------------------------------------------------------
template <int AF32, int ACT, int OUTF32>
__global__ __launch_bounds__(256) void gemm_bt(
    const void* A0_, const void* A1_,
    const short* __restrict__ B0, const short* __restrict__ B1,
    const float* __restrict__ b0, const float* __restrict__ b1,
    void* C0_, void* C1_,
    float s0, float s1, int N, int K)
{
    const int z = blockIdx.z;
    const void* A_ = z ? A1_ : A0_;
    const short* B = z ? B1 : B0;
    const float* bias = z ? b1 : b0;
    void* C_ = z ? C1_ : C0_;
    const float scale = z ? s1 : s0;

    const int bm = blockIdx.y * 128;
    const int bn = blockIdx.x * 128;
    const int tid = threadIdx.x;
    const int w = tid >> 6;
    const int lane = tid & 63;
    const int l15 = lane & 15, quad = lane >> 4;
    const int wm = (w >> 1) * 64, wn = (w & 1) * 64;

    __shared__ __align__(16) short As[128 * 32];
    __shared__ __align__(16) short Bs[128 * 32];

    f32x4 acc[4][4];
#pragma unroll
    for (int mt = 0; mt < 4; ++mt)
#pragma unroll
        for (int nt = 0; nt < 4; ++nt) acc[mt][nt] = (f32x4){0.f, 0.f, 0.f, 0.f};

    const int ga0 = tid * 2;

    for (int k0 = 0; k0 < K; k0 += 32) {
#pragma unroll
        for (int i = 0; i < 2; ++i) {
            int ga = ga0 + i;
            int row = ga >> 2, g = ga & 3;
            short8 aval;
            if (AF32) {
                const float* ap = (const float*)A_ + (size_t)(bm + row) * K + k0 + g * 8;
                float4 f0 = *(const float4*)ap;
                float4 f1 = *(const float4*)(ap + 4);
                aval[0] = f2bf(f0.x); aval[1] = f2bf(f0.y);
                aval[2] = f2bf(f0.z); aval[3] = f2bf(f0.w);
                aval[4] = f2bf(f1.x); aval[5] = f2bf(f1.y);
                aval[6] = f2bf(f1.z); aval[7] = f2bf(f1.w);
            } else {
                aval = *(const short8*)((const short*)A_ + (size_t)(bm + row) * K + k0 + g * 8);
            }
            *(short8*)(void*)&As[row * 32 + ((g ^ (row & 3)) * 8)] = aval;
            short8 bval = *(const short8*)(const void*)&B[(size_t)(bn + row) * K + k0 + g * 8];
            *(short8*)(void*)&Bs[row * 32 + ((g ^ (row & 3)) * 8)] = bval;
        }
        __syncthreads();

        bf16x8 af[4], bfr[4];
#pragma unroll
        for (int t = 0; t < 4; ++t) {
            af[t] = __builtin_bit_cast(bf16x8,
                *(const short8*)(const void*)&As[(wm + t * 16 + l15) * 32 + ((quad ^ (l15 & 3)) * 8)]);
            bfr[t] = __builtin_bit_cast(bf16x8,
                *(const short8*)(const void*)&Bs[(wn + t * 16 + l15) * 32 + ((quad ^ (l15 & 3)) * 8)]);
        }
#pragma unroll
        for (int mt = 0; mt < 4; ++mt)
#pragma unroll
            for (int nt = 0; nt < 4; ++nt)
                acc[mt][nt] = __builtin_amdgcn_mfma_f32_16x16x32_bf16(af[mt], bfr[nt], acc[mt][nt], 0, 0, 0);
        __syncthreads();
    }

    float bv[4];
#pragma unroll
    for (int nt = 0; nt < 4; ++nt) bv[nt] = bias[bn + wn + nt * 16 + l15];
#pragma unroll
    for (int mt = 0; mt < 4; ++mt)
#pragma unroll
        for (int r = 0; r < 4; ++r) {
            int row = bm + wm + mt * 16 + quad * 4 + r;
#pragma unroll
            for (int nt = 0; nt < 4; ++nt) {
                float v = acc[mt][nt][r] + bv[nt];
                if (ACT) v = gelu_f(v);
                v *= scale;
                int col = bn + wn + nt * 16 + l15;
                if (OUTF32) ((float*)C_)[(size_t)row * N + col] = v;
                else        ((short*)C_)[(size_t)row * N + col] = f2bf(v);
            }
        }
}

// ---------------------------------------------------------------------------
// K repack: kbb bf16 [8192][256] -> kfr frag-major
// kfr[((bh*64 + kt)*4 + (nt*2+ks))*512 + lane*8 + j]:
//   key = kt*64 + nt*32 + (lane&31), k = ks*16 + (lane>>5)*8 + j
// ---------------------------------------------------------------------------
__global__ __launch_bounds__(256) void repack_k(
    const short* __restrict__ kb, short* __restrict__ kfr)
{
    const int kt = blockIdx.x, bh = blockIdx.y;
    const int b = bh >> 3, h = bh & 7;
    const int t = threadIdx.x;
    const int c = t >> 6, l = t & 63;
    const int nt = c >> 1, ks = c & 1;
    int key = kt * 64 + nt * 32 + (l & 31);
    int k = ks * 16 + (l >> 5) * 8;
    short8 v = *(const short8*)(const void*)&kb[(size_t)(b * 4096 + key) * 256 + h * 32 + k];
    *(short8*)(void*)&kfr[((((size_t)bh * 64 + kt) * 4 + c) * 64 + l) * 8] = v;
}

// ---------------------------------------------------------------------------
// V repack: vbb bf16 [8192][512] -> vfr frag-major (B-operand for PV)
// vfr[((bh*64 + kt)*8 + (dt*4+ks))*512 + lane*8 + j]:
//   dk = dt*32 + (lane&31), key(within kt tile) = ks*16 + (lane>>5)*8 + j
// ---------------------------------------------------------------------------
__global__ __launch_bounds__(256) void repack_v(
    const short* __restrict__ vbb, short* __restrict__ vfr)
{
    const int kt = blockIdx.x, bh = blockIdx.y;
    const int b = bh >> 3, h = bh & 7;
    const int t = threadIdx.x;
    __shared__ short Vt[64][72];   // [key][dk]

#pragma unroll
    for (int it = 0; it < 2; ++it) {
        int idx = t + it * 256;
        int keyr = idx >> 3, c8 = (idx & 7) * 8;
        *(short8*)(void*)&Vt[keyr][c8] =
            *(const short8*)(const void*)&vbb[(size_t)(b * 4096 + kt * 64 + keyr) * 512 + h * 64 + c8];
    }
    __syncthreads();
#pragma unroll
    for (int it = 0; it < 2; ++it) {
        int chunk = (t >> 6) * 2 + it;
        int l = t & 63;
        int dt = chunk >> 2, ks = chunk & 3;
        short8 o;
#pragma unroll
        for (int j = 0; j < 8; ++j)
            o[j] = Vt[ks * 16 + (l >> 5) * 8 + j][dt * 32 + (l & 31)];
        *(short8*)(void*)&vfr[((((size_t)bh * 64 + kt) * 8 + chunk) * 64 + l) * 8] = o;
    }
}

// ---------------------------------------------------------------------------
// Flash attention, 32x32x16 MFMA, no-max softmax via exp2 (q pre-scaled by
// log2(e)/sqrt(32)). Block = 4 waves = 128 q rows; each wave owns 32 q rows.
// qb: bf16 [8192][256]; kfr/vfr: frag-major; xb3: bf16 [8192][1536] hi|hi|lo.
// ---------------------------------------------------------------------------
__global__ __launch_bounds__(256) void flash_mfma32(
    const short* __restrict__ qb, const short* __restrict__ kfr,
    const short* __restrict__ vfr, short* __restrict__ xb3)
{
    const int qt = blockIdx.x;   // 0..31, 128 q rows
    const int bh = blockIdx.y;   // 0..15
    const int b = bh >> 3, h = bh & 7;
    const int tid = threadIdx.x;
    const int w = tid >> 6;
    const int lane = tid & 63;
    const int l31 = lane & 31;
    const int half = lane >> 5;

    __shared__ __align__(16) short KV[12 * 512];     // chunks 0..3 = K, 4..11 = V
    __shared__ __align__(16) short Pls[4][32 * 68];  // per-wave P [32 q][64 key+pad]

    // Q A-frags (k 0..15 and 16..31), direct from global (row stride 512B)
    const short* qrow = qb + (size_t)(b * 4096 + qt * 128 + w * 32 + l31) * 256 + h * 32 + half * 8;
    bf16x8 qf0 = __builtin_bit_cast(bf16x8, *(const short8*)(const void*)qrow);
    bf16x8 qf1 = __builtin_bit_cast(bf16x8, *(const short8*)(const void*)(qrow + 16));

    f32x16 O0{}, O1{};
    float la[16];
#pragma unroll
    for (int r = 0; r < 16; ++r) la[r] = 0.f;

    const short* kbase = kfr + ((size_t)bh * 64) * 4 * 512;
    const short* vbase = vfr + ((size_t)bh * 64) * 8 * 512;
    short* Pw = Pls[w];

#pragma unroll 1
    for (int kt = 0; kt < 64; ++kt) {
        __syncthreads();   // previous iteration's KV reads done
        // stage 12 chunks (3 per wave), coalesced 16B/lane copies
#pragma unroll
        for (int i = 0; i < 3; ++i) {
            int c = w * 3 + i;
            const short* g = (c < 4)
                ? (kbase + ((size_t)kt * 4 + c) * 512 + lane * 8)
                : (vbase + ((size_t)kt * 8 + (c - 4)) * 512 + lane * 8);
            *(short8*)(void*)&KV[c * 512 + lane * 8] = *(const short8*)(const void*)g;
        }
        __syncthreads();

        // QK^T: scores [32 q][64 keys] = 2 n-tiles, K=32 in 2 MFMA steps
        f32x16 zero{};
        bf16x8 kf;
        kf = __builtin_bit_cast(bf16x8, *(const short8*)(const void*)&KV[0 * 512 + lane * 8]);
        f32x16 s0 = __builtin_amdgcn_mfma_f32_32x32x16_bf16(qf0, kf, zero, 0, 0, 0);
        kf = __builtin_bit_cast(bf16x8, *(const short8*)(const void*)&KV[1 * 512 + lane * 8]);
        s0 = __builtin_amdgcn_mfma_f32_32x32x16_bf16(qf1, kf, s0, 0, 0, 0);
        kf = __builtin_bit_cast(bf16x8, *(const short8*)(const void*)&KV[2 * 512 + lane * 8]);
        f32x16 s1 = __builtin_amdgcn_mfma_f32_32x32x16_bf16(qf0, kf, zero, 0, 0, 0);
        kf = __builtin_bit_cast(bf16x8, *(const short8*)(const void*)&KV[3 * 512 + lane * 8]);
        s1 = __builtin_amdgcn_mfma_f32_32x32x16_bf16(qf1, kf, s1, 0, 0, 0);

        // exp2 (scores bounded, no max needed) + l accumulate + P -> LDS bf16
#pragma unroll
        for (int r = 0; r < 16; ++r) {
            float p0 = exp2f(s0[r]);
            float p1 = exp2f(s1[r]);
            la[r] += p0 + p1;
            int qr = (r & 3) + 8 * (r >> 2) + 4 * half;  // C-layout row
            Pw[qr * 68 + l31] = f2bf(p0);
            Pw[qr * 68 + 32 + l31] = f2bf(p1);
        }

        // PV: A-frags from wave-private P (no barrier needed)
        bf16x8 pf[4];
#pragma unroll
        for (int ks = 0; ks < 4; ++ks)
            pf[ks] = __builtin_bit_cast(bf16x8,
                *(const short8*)(const void*)&Pw[l31 * 68 + ks * 16 + half * 8]);
#pragma unroll
        for (int ks = 0; ks < 4; ++ks) {
            bf16x8 vf = __builtin_bit_cast(bf16x8,
                *(const short8*)(const void*)&KV[(4 + ks) * 512 + lane * 8]);
            O0 = __builtin_amdgcn_mfma_f32_32x32x16_bf16(pf[ks], vf, O0, 0, 0, 0);
        }
#pragma unroll
        for (int ks = 0; ks < 4; ++ks) {
            bf16x8 vf = __builtin_bit_cast(bf16x8,
                *(const short8*)(const void*)&KV[(8 + ks) * 512 + lane * 8]);
            O1 = __builtin_amdgcn_mfma_f32_32x32x16_bf16(pf[ks], vf, O1, 0, 0, 0);
        }
    }

    // epilogue: reduce l over the 32 key-lanes, normalize, split-store
    float inv[16];
#pragma unroll
    for (int r = 0; r < 16; ++r) {
        float t = la[r];
        t += __shfl_xor(t, 1);
        t += __shfl_xor(t, 2);
        t += __shfl_xor(t, 4);
        t += __shfl_xor(t, 8);
        t += __shfl_xor(t, 16);
        inv[r] = 1.f / t;
    }
#pragma unroll
    for (int r = 0; r < 16; ++r) {
        int qr = (r & 3) + 8 * (r >> 2) + 4 * half;
        size_t row = (size_t)(b * 4096 + qt * 128 + w * 32 + qr);
#pragma unroll
        for (int dt = 0; dt < 2; ++dt) {
            float xv = (dt ? O1[r] : O0[r]) * inv[r];
            short hi = f2bf(xv);
            short lo = f2bf(xv - bf2f(hi));
            short* d = xb3 + row * 1536 + h * 64 + dt * 32 + l31;
            d[0] = hi;
            d[512] = hi;
            d[1024] = lo;
        }
    }
}

// ---------------------------------------------------------------------------
extern "C" void kernel_launch(void* const* d_in, const int* in_sizes, int n_in,
                              void* d_out, int out_size, void* d_ws, size_t ws_size,
                              hipStream_t stream)
{
    const float* query = (const float*)d_in[0];
    const float* key   = (const float*)d_in[1];
    const float* value = (const float*)d_in[2];
    const float* Wq1   = (const float*)d_in[3];
    const float* bq1   = (const float*)d_in[4];
    const float* Wq2   = (const float*)d_in[5];
    const float* bq2   = (const float*)d_in[6];
    const float* Wk1   = (const float*)d_in[7];
    const float* bk1   = (const float*)d_in[8];
    const float* Wk2   = (const float*)d_in[9];
    const float* bk2   = (const float*)d_in[10];
    const float* Wv    = (const float*)d_in[11];
    const float* bv    = (const float*)d_in[12];
    const float* Wo    = (const float*)d_in[13];
    const float* bo    = (const float*)d_in[14];
    float* out = (float*)d_out;

    // Workspace (bytes), total 68 MB:
    char* ws = (char*)d_ws;
    short* H1q  = (short*)(ws + 0);            // 16 MB   (dead after mlp2)
    short* H1k  = (short*)(ws + 16777216);     // 16 MB   (dead after mlp2)
    short* xb3  = (short*)(ws + 0);            // 25,165,824 (overlays H1)
    short* qbb  = (short*)(ws + 33554432);     // 4 MB
    short* kbb  = (short*)(ws + 37748736);     // 4 MB
    short* vbb  = (short*)(ws + 41943040);     // 8 MB
    short* kfr  = (short*)(ws + 50331648);     // 4 MB
    short* vfr  = (short*)(ws + 54525952);     // 8 MB
    short* Wq1t = (short*)(ws + 62914560);     // 1 MB
    short* Wk1t = (short*)(ws + 63963136);     // 1 MB
    short* Wq2t = (short*)(ws + 65011712);     // 512 KB
    short* Wk2t = (short*)(ws + 65536000);     // 512 KB
    short* Wvt  = (short*)(ws + 66060288);     // 512 KB
    short* Wo3t = (short*)(ws + 66584576);     // 1.5 MB -> end 68,157,440

    dim3 blk(256);
    // 1/sqrt(32) * log2(e)  (exp2-based softmax)
    const float qscale = 0.17677669529663687f * 1.4426950408889634f;

    // weight prep
    wcast_t<<<dim3(32, 16), blk, 0, stream>>>(Wq1, Wq1t, 512, 1024);
    wcast_t<<<dim3(32, 16), blk, 0, stream>>>(Wk1, Wk1t, 512, 1024);
    wcast_t<<<dim3(8, 32), blk, 0, stream>>>(Wq2, Wq2t, 1024, 256);
    wcast_t<<<dim3(8, 32), blk, 0, stream>>>(Wk2, Wk2t, 1024, 256);
    wcast_t<<<dim3(16, 16), blk, 0, stream>>>(Wv, Wvt, 512, 512);
    wcast_t3<<<dim3(16, 16), blk, 0, stream>>>(Wo, Wo3t, 512, 512);

    // MLP layer 1 (q & k batched): f32 A, GELU, bf16 out. N=1024, K=512
    gemm_bt<1, 1, 0><<<dim3(8, 64, 2), blk, 0, stream>>>(
        query, key, Wq1t, Wk1t, bq1, bk1, H1q, H1k, 1.f, 1.f, 1024, 512);
    // MLP layer 2 (q & k batched): q pre-scaled by qscale. N=256, K=1024
    gemm_bt<0, 0, 0><<<dim3(2, 64, 2), blk, 0, stream>>>(
        H1q, H1k, Wq2t, Wk2t, bq2, bk2, qbb, kbb, qscale, 1.f, 256, 1024);
    // v projection, plain bf16 (f32 A cast in staging). N=512, K=512
    gemm_bt<1, 0, 0><<<dim3(4, 64, 1), blk, 0, stream>>>(
        value, value, Wvt, Wvt, bv, bv, vbb, vbb, 1.f, 1.f, 512, 512);
    // frag-major repacks for flash
    repack_k<<<dim3(64, 16), blk, 0, stream>>>(kbb, kfr);
    repack_v<<<dim3(64, 16), blk, 0, stream>>>(vbb, vfr);
    // attention (writes split xb3 directly)
    flash_mfma32<<<dim3(32, 16), blk, 0, stream>>>(qbb, kfr, vfr, xb3);
    // output projection, split-bf16 (K=1536) -> f32
    gemm_bt<0, 0, 1><<<dim3(4, 64, 1), blk, 0, stream>>>(
        xb3, xb3, Wo3t, Wo3t, bo, bo, out, out, 1.f, 1.f, 512, 1536);
}